// Round 1
// baseline (492.140 us; speedup 1.0000x reference)
//
#include <hip/hip_runtime.h>
#include <hip/hip_bf16.h>

// Problem: NX=128, NU=64, NY=32, N=262144. Inputs fp32, output fp32 (proven R1/R2:
// bf16-interp of inputs -> NaN; bf16-packed output -> sqrt(2)*max error signature).
// dx = x@A^T + u@B^T ; y = x@C^T
// A=(-0.5(Q+G^TG+eps I)+S)@P ; B=sqrtm(Q)@(H/(1.01*sqrt(lmax(HH^T)))) ; C=G@P
// Pack W[160][192] = [A|B ; C|0] bf16; one HBM-bound MFMA GEMM over N, fp32 out.
// sqrtm via degree-32 Chebyshev of sqrt applied to Htilde (B-term small vs dx ~400).
// R3: lamQ/lamH via fused UNNORMALIZED power iteration (1 barrier/step, 32 steps,
//     Q on tid<512 / HtH on tid>=512 concurrently) instead of 2x24 normalized
//     rounds (3 barriers each). k_main occupancy 2->3 blocks/CU.

#define NB 262144

typedef __attribute__((ext_vector_type(8))) short s8v;
typedef __attribute__((ext_vector_type(4))) short s4v;
typedef __attribute__((ext_vector_type(4))) float f4v;

__device__ __forceinline__ float bf2f(unsigned short s) {
  unsigned int u = ((unsigned int)s) << 16;
  return __uint_as_float(u);
}
__device__ __forceinline__ unsigned short f2bf(float f) {
  unsigned int u = __float_as_uint(f);
  u += 0x7fffu + ((u >> 16) & 1u);
  return (unsigned short)(u >> 16);
}

// ---------------- prep1: M = -0.5(Q+G^TG+eps I)+S (fp32), HtH (fp32), W zero pad ----------------
__global__ __launch_bounds__(256) void k_prep1(
    const float* __restrict__ Q, const float* __restrict__ S,
    const float* __restrict__ G, const float* __restrict__ H,
    float* __restrict__ Mf, float* __restrict__ HtH, unsigned short* __restrict__ W)
{
  const int bid = blockIdx.x, tid = threadIdx.x;
  if (bid < 64) {
    const int idx = bid * 256 + tid;
    const int j = idx >> 7, k = idx & 127;
    float g = 0.f;
    #pragma unroll 4
    for (int i = 0; i < 32; ++i)
      g += G[i * 128 + j] * G[i * 128 + k];
    Mf[idx] = -0.5f * (Q[idx] + g + ((j == k) ? 1e-4f : 0.f)) + S[idx];
  } else {
    const int e = (bid - 64) * 256 + tid;  // 0..4095
    const int a = e >> 6, b = e & 63;
    float s = 0.f;
    #pragma unroll 4
    for (int r = 0; r < 128; ++r)
      s += H[r * 64 + a] * H[r * 64 + b];
    HtH[e] = s;
    if (bid == 64) {
      for (int i = 0; i < 8; ++i) {
        int e2 = i * 256 + tid;  // 0..2047
        int n = 128 + (e2 >> 6), kk = 128 + (e2 & 63);
        W[n * 192 + kk] = 0;
      }
    }
  }
}

// ---------------- prepAC: A = M@P, C = G@P -> W (bf16) ----------------
__global__ __launch_bounds__(256) void k_prepAC(
    const float* __restrict__ Mf, const float* __restrict__ P,
    const float* __restrict__ G, unsigned short* __restrict__ W)
{
  const int bid = blockIdx.x, tid = threadIdx.x;
  if (bid < 64) {
    const int idx = bid * 256 + tid;
    const int n = idx >> 7, k = idx & 127;
    float s = 0.f;
    #pragma unroll 4
    for (int l = 0; l < 128; ++l)
      s += Mf[n * 128 + l] * P[l * 128 + k];
    W[n * 192 + k] = f2bf(s);
  } else {
    for (int i = 0; i < 4; ++i) {
      int e = (bid - 64) * 1024 + i * 256 + tid;  // 0..4095
      int j = e >> 7, k = e & 127;
      float s = 0.f;
      #pragma unroll 4
      for (int l = 0; l < 128; ++l)
        s += G[j * 128 + l] * P[l * 128 + k];
      W[(128 + j) * 192 + k] = f2bf(s);
    }
  }
}

// ---------------- prep23: fused power iteration + Chebyshev sqrtm(Q)@Htilde -> W B-part ----------------
__global__ __launch_bounds__(1024) void k_prep23(
    const float* __restrict__ Qg, const float* __restrict__ Hg,
    const float* __restrict__ HtHg, unsigned short* __restrict__ W)
{
  __shared__ char smem[65536];
  unsigned short* Xs = (unsigned short*)smem;            // [0,32768): 128x128 swizzled
  unsigned short* V0s = (unsigned short*)(smem + 32768); // 64x128 swizzled (V^T)
  unsigned short* V1s = (unsigned short*)(smem + 49152);
  float* vQ = (float*)(smem + 32768);   // overlap V region (power phase only)
  float* wQ = (float*)(smem + 33280);
  float* vH = (float*)(smem + 33792);
  float* wH = (float*)(smem + 34048);
  float* red = (float*)(smem + 34304);
  float* HtHs = (float*)(smem + 49152); // overlaps V1s (power phase only)

  const int tid = threadIdx.x;
  const int lane = tid & 63;
  const int wv = tid >> 6;

  // load Q -> Xs (swizzled: logical chunk c of row m stored at chunk c ^ (m&7))
  for (int i = 0; i < 16; ++i) {
    int e = i * 1024 + tid;
    int m = e >> 7, k = e & 127;
    Xs[m * 128 + (((k >> 3) ^ (m & 7)) << 3) + (k & 7)] = f2bf(Qg[e]);
  }
  // HtH prescaled by 1/256 so 32 unnormalized matvecs stay in fp32 range
  for (int i = 0; i < 4; ++i) HtHs[i * 1024 + tid] = HtHg[i * 1024 + tid] * 0.00390625f;
  if (tid < 128) vQ[tid] = (float)((tid * 1103515245u + 12345u) & 0xffffu) * (1.f / 65536.f) + 0.05f;
  if (tid < 64)  vH[tid] = (float)((tid * 2654435761u + 911u) & 0xffffu) * (1.f / 65536.f) + 0.05f;
  __syncthreads();

  // ---- fused unnormalized power iteration: Q on tid<512, HtH on tid>=512 ----
  // 32 steps, ONE barrier per step. Exact 2^-k rescale at step 16 (range control
  // only; lam read from ||v32||/||v31||, both post-rescale, so ratio unaffected).
  float* qin = vQ; float* qout = wQ;
  float* hin = vH; float* hout = wH;
  for (int it = 0; it < 32; ++it) {
    if (tid < 512) {
      const int row = tid >> 2, sub = tid & 3;   // 128 rows x 4 subs (32 k each)
      float p = 0.f;
      #pragma unroll
      for (int c = 0; c < 4; ++c) {
        const int ch = sub * 4 + c;
        const s8v q = *(const s8v*)&Xs[row * 128 + ((ch ^ (row & 7)) << 3)];
        const f4v a = *(const f4v*)&qin[ch * 8];
        const f4v b = *(const f4v*)&qin[ch * 8 + 4];
        p += bf2f((unsigned short)q[0]) * a[0];
        p += bf2f((unsigned short)q[1]) * a[1];
        p += bf2f((unsigned short)q[2]) * a[2];
        p += bf2f((unsigned short)q[3]) * a[3];
        p += bf2f((unsigned short)q[4]) * b[0];
        p += bf2f((unsigned short)q[5]) * b[1];
        p += bf2f((unsigned short)q[6]) * b[2];
        p += bf2f((unsigned short)q[7]) * b[3];
      }
      p += __shfl_xor(p, 1); p += __shfl_xor(p, 2);
      if (it == 16) p *= 0x1p-32f;
      if (sub == 0) qout[row] = p;
    } else {
      const int idx = tid - 512;
      const int row = idx >> 3, sub = idx & 7;   // 64 rows x 8 subs (8 k each)
      const f4v a  = *(const f4v*)&HtHs[row * 64 + sub * 8];
      const f4v b  = *(const f4v*)&HtHs[row * 64 + sub * 8 + 4];
      const f4v va = *(const f4v*)&hin[sub * 8];
      const f4v vb = *(const f4v*)&hin[sub * 8 + 4];
      float p = a[0] * va[0] + a[1] * va[1] + a[2] * va[2] + a[3] * va[3]
              + b[0] * vb[0] + b[1] * vb[1] + b[2] * vb[2] + b[3] * vb[3];
      p += __shfl_xor(p, 1); p += __shfl_xor(p, 2); p += __shfl_xor(p, 4);
      if (it == 16) p *= 0x1p-8f;
      if (sub == 0) hout[row] = p;
    }
    __syncthreads();
    float* t;
    t = qin; qin = qout; qout = t;
    t = hin; hin = hout; hout = t;
  }
  // after loop: qin = v32, qout = v31 (same for hin/hout)

  // ---- norms of last two iterates -> lamQ, lamH ----
  {
    float s = 0.f;
    if (wv == 0)      { float a = qin[lane],  b = qin[lane + 64];  s = a * a + b * b; }
    else if (wv == 1) { float a = qout[lane], b = qout[lane + 64]; s = a * a + b * b; }
    else if (wv == 2) { float a = hin[lane];  s = a * a; }
    else if (wv == 3) { float a = hout[lane]; s = a * a; }
    if (wv < 4) {
      s += __shfl_xor(s, 1); s += __shfl_xor(s, 2); s += __shfl_xor(s, 4);
      s += __shfl_xor(s, 8); s += __shfl_xor(s, 16); s += __shfl_xor(s, 32);
      if (lane == 0) red[wv] = s;
    }
  }
  __syncthreads();
  if (tid == 0) {
    red[4] = sqrtf(red[0] / red[1]);           // lamQ
    red[5] = 256.f * sqrtf(red[2] / red[3]);   // lamH (undo 1/256 prescale)
  }
  __syncthreads();
  const float bb = 1.10f * red[4];   // Chebyshev interval [0, bb]
  const float sqrtb = sqrtf(bb);
  const float invden = 1.f / (1.01f * sqrtf(red[5]));
  __syncthreads();  // all threads hold bb/invden in regs before V0s clobbers red

  // ---- phase C: X = (2/b)Q - I in place; V0 = Htilde^T; Chebyshev recurrence ----
  for (int i = 0; i < 16; ++i) {
    int e = i * 1024 + tid;
    int m = e >> 7, k = e & 127;
    int a = m * 128 + (((k >> 3) ^ (m & 7)) << 3) + (k & 7);
    float q = bf2f(Xs[a]);
    Xs[a] = f2bf(q * (2.f / bb) - ((m == k) ? 1.f : 0.f));
  }
  for (int i = 0; i < 8; ++i) {
    int e = i * 1024 + tid;
    int j = e & 63, m = e >> 6;
    V0s[j * 128 + (((m >> 3) ^ (j & 7)) << 3) + (m & 7)] = f2bf(Hg[m * 64 + j] * invden);
  }
  const int t0 = wv * 2;   // 2 of 32 16x16 tiles per wave (8 m-tiles x 4 n-tiles)
  float baccR[2][4];
  #pragma unroll
  for (int tt = 0; tt < 2; ++tt) {
    int mt = (t0 + tt) >> 2, nt = (t0 + tt) & 3;
    int n = nt * 16 + (lane & 15);
    int mb = mt * 16 + ((lane >> 4) << 2);
    #pragma unroll
    for (int i = 0; i < 4; ++i)
      baccR[tt][i] = 0.63661977f * Hg[(mb + i) * 64 + n] * invden;  // a0 * T0 term
  }
  __syncthreads();

  unsigned short* Vc = V0s;
  unsigned short* Vp = V1s;
  for (int k = 1; k <= 32; ++k) {
    const float ck = ((k & 1) ? 1.0f : -1.0f) / (3.14159265f * ((float)(k * k) - 0.25f));
    #pragma unroll
    for (int tt = 0; tt < 2; ++tt) {
      const int mt = (t0 + tt) >> 2, nt = (t0 + tt) & 3;
      f4v acc = {0.f, 0.f, 0.f, 0.f};
      const int arow = mt * 16 + (lane & 15);
      const int brow = nt * 16 + (lane & 15);
      #pragma unroll
      for (int ks = 0; ks < 4; ++ks) {
        int kc = ks * 4 + (lane >> 4);
        s8v af = *(const s8v*)&Xs[arow * 128 + ((kc ^ (arow & 7)) << 3)];
        s8v bf = *(const s8v*)&Vc[brow * 128 + ((kc ^ (brow & 7)) << 3)];
        acc = __builtin_amdgcn_mfma_f32_16x16x32_bf16(af, bf, acc, 0, 0, 0);
      }
      const int n = brow;
      const int mb = mt * 16 + ((lane >> 4) << 2);
      const int vaddr = n * 128 + (((mb >> 3) ^ (n & 7)) << 3) + (mb & 7);
      float nv[4];
      if (k == 1) {
        #pragma unroll
        for (int i = 0; i < 4; ++i) nv[i] = acc[i];
      } else {
        s4v ov = *(const s4v*)&Vp[vaddr];
        #pragma unroll
        for (int i = 0; i < 4; ++i) nv[i] = 2.f * acc[i] - bf2f((unsigned short)ov[i]);
      }
      s4v st;
      #pragma unroll
      for (int i = 0; i < 4; ++i) { st[i] = (short)f2bf(nv[i]); baccR[tt][i] += ck * nv[i]; }
      *(s4v*)&Vp[vaddr] = st;
    }
    __syncthreads();
    unsigned short* t = Vc; Vc = Vp; Vp = t;
  }

  // ---- phase D: B = sqrt(b) * sum -> W[m][128+j] ----
  #pragma unroll
  for (int tt = 0; tt < 2; ++tt) {
    const int mt = (t0 + tt) >> 2, nt = (t0 + tt) & 3;
    const int n = nt * 16 + (lane & 15);
    const int mb = mt * 16 + ((lane >> 4) << 2);
    #pragma unroll
    for (int i = 0; i < 4; ++i)
      W[(mb + i) * 192 + 128 + n] = f2bf(sqrtb * baccR[tt][i]);
  }
}

// ---------------- main: Out[N][160] = [x|u] @ W^T ; fp32 in, fp32 out ----------------
// LDS 51200 B -> 3 blocks/CU fit (153600 <= 163840); VGPR 112 <= 512/3, no spill.
__global__ __launch_bounds__(256, 3) void k_main(
    const float* __restrict__ x, const float* __restrict__ u,
    const unsigned short* __restrict__ W, float* __restrict__ out)
{
  __shared__ char smraw[128 * 200 * 2];          // 51200 B
  unsigned short* sm = (unsigned short*)smraw;    // staging: [128 rows][200], cols 0..127 x, 128..191 u
  float* fb = (float*)smraw;                      // epilogue reuse: [64 rows][164] fp32 = 41984 B

  const int tid = threadIdx.x, lane = tid & 63, w = tid >> 6;
  const int mw = w & 1, nw = w >> 1;
  const int base = blockIdx.x * 128;

  // weight fragments: this wave's 5 n-tiles x 6 k-steps, registers for whole block
  s8v wf[5][6];
  {
    const int n0 = nw * 80 + (lane & 15);
    const int kof = (lane >> 4) * 8;
    #pragma unroll
    for (int nt = 0; nt < 5; ++nt)
      #pragma unroll
      for (int ks = 0; ks < 6; ++ks)
        wf[nt][ks] = *(const s8v*)&W[(n0 + nt * 16) * 192 + ks * 32 + kof];
  }
  // stage x,u tiles: fp32 16B loads, convert to bf16
  #pragma unroll
  for (int p = 0; p < 16; ++p) {
    int g = p * 256 + tid; int r = g >> 5, c = g & 31;
    f4v v = *(const f4v*)&x[(size_t)(base + r) * 128 + c * 4];
    s4v b;
    #pragma unroll
    for (int i = 0; i < 4; ++i) b[i] = (short)f2bf(v[i]);
    *(s4v*)&sm[r * 200 + c * 4] = b;
  }
  #pragma unroll
  for (int p = 0; p < 8; ++p) {
    int g = p * 256 + tid; int r = g >> 4, c = g & 15;
    f4v v = *(const f4v*)&u[(size_t)(base + r) * 64 + c * 4];
    s4v b;
    #pragma unroll
    for (int i = 0; i < 4; ++i) b[i] = (short)f2bf(v[i]);
    *(s4v*)&sm[r * 200 + 128 + c * 4] = b;
  }
  __syncthreads();

  f4v acc[4][5];
  #pragma unroll
  for (int mt = 0; mt < 4; ++mt)
    #pragma unroll
    for (int nt = 0; nt < 5; ++nt)
      acc[mt][nt] = (f4v){0.f, 0.f, 0.f, 0.f};

  #pragma unroll
  for (int mt = 0; mt < 4; ++mt) {
    const int row = mw * 64 + mt * 16 + (lane & 15);
    const int kof = (lane >> 4) * 8;
    #pragma unroll
    for (int ks = 0; ks < 6; ++ks) {
      s8v af = *(const s8v*)&sm[row * 200 + ks * 32 + kof];
      #pragma unroll
      for (int nt = 0; nt < 5; ++nt)
        acc[mt][nt] = __builtin_amdgcn_mfma_f32_16x16x32_bf16(af, wf[nt][ks], acc[mt][nt], 0, 0, 0);
    }
  }

  // epilogue: two passes of 64 rows through fp32 LDS, then coalesced float4 stores
  float* const yout = out + (size_t)NB * 128;
  #pragma unroll
  for (int pass = 0; pass < 2; ++pass) {
    __syncthreads();
    if (mw == pass) {
      #pragma unroll
      for (int mt = 0; mt < 4; ++mt)
        #pragma unroll
        for (int nt = 0; nt < 5; ++nt) {
          const int rr = mt * 16 + ((lane >> 4) << 2);        // row within this 64-row pass
          const int cc = nw * 80 + nt * 16 + (lane & 15);
          #pragma unroll
          for (int i = 0; i < 4; ++i)
            fb[(rr + i) * 164 + cc] = acc[mt][nt][i];
        }
    }
    __syncthreads();
    const int rb = base + pass * 64;
    #pragma unroll
    for (int p = 0; p < 8; ++p) {   // dx: 64 rows x 128 cols fp32
      int g = p * 256 + tid; int r = g >> 5, c = g & 31;
      *(f4v*)&out[(size_t)(rb + r) * 128 + c * 4] = *(const f4v*)&fb[r * 164 + c * 4];
    }
    #pragma unroll
    for (int p = 0; p < 2; ++p) {   // y: 64 rows x 32 cols fp32
      int g = p * 256 + tid; int r = g >> 3, c = g & 7;
      *(f4v*)&yout[(size_t)(rb + r) * 32 + c * 4] = *(const f4v*)&fb[r * 164 + 128 + c * 4];
    }
  }
}

extern "C" void kernel_launch(void* const* d_in, const int* in_sizes, int n_in,
                              void* d_out, int out_size, void* d_ws, size_t ws_size,
                              hipStream_t stream) {
  // identify unambiguous inputs by element count (insurance against ordering surprises);
  // the three 128x128 matrices keep dict order Q,P,S per harness contract.
  const float *u = nullptr, *x = nullptr, *G = nullptr, *H = nullptr;
  const float* sq[3] = {nullptr, nullptr, nullptr};
  int nsq = 0;
  for (int i = 0; i < n_in; ++i) {
    const float* p = (const float*)d_in[i];
    switch (in_sizes[i]) {
      case NB * 64:  u = p; break;
      case NB * 128: x = p; break;
      case 32 * 128: G = p; break;
      case 128 * 64: H = p; break;
      case 128 * 128: if (nsq < 3) sq[nsq++] = p; break;
      default: break;
    }
  }
  const float* Q = sq[0];
  const float* P = sq[1];
  const float* S = sq[2];

  char* ws = (char*)d_ws;
  unsigned short* W = (unsigned short*)ws;        // 160*192 bf16 = 61440 B
  float* HtH = (float*)(ws + 61440);              // 64*64 fp32  = 16384 B
  float* Mf  = (float*)(ws + 77824);              // 128*128 fp32 = 65536 B
  float* out = (float*)d_out;

  k_prep1 <<<80,   256,  0, stream>>>(Q, S, G, H, Mf, HtH, W);
  k_prepAC<<<68,   256,  0, stream>>>(Mf, P, G, W);
  k_prep23<<<1,    1024, 0, stream>>>(Q, H, HtH, W);
  k_main  <<<2048, 256,  0, stream>>>(x, u, W, out);
}

// Round 4
// 436.965 us; speedup vs baseline: 1.1263x; 1.1263x over previous
//
#include <hip/hip_runtime.h>
#include <hip/hip_bf16.h>

// Problem: NX=128, NU=64, NY=32, N=262144. Inputs fp32, output fp32 (proven R1/R2:
// bf16-interp of inputs -> NaN; bf16-packed output -> sqrt(2)*max error signature).
// dx = x@A^T + u@B^T ; y = x@C^T
// A=(-0.5(Q+G^TG+eps I)+S)@P ; B=sqrtm(Q)@(H/(1.01*sqrt(lmax(HH^T)))) ; C=G@P
// Pack W[160][192] = [A|B ; C|0] bf16; one HBM-bound MFMA GEMM over N, fp32 out.
// R3: fused unnormalized power iteration in prep23 (kept).
// R4: k_main register restructure. R1 lesson: wf[5][6] (120 VGPR) live across
//   mt-loop + acc (80 AGPR) can't fit the 168-reg budget of 3 waves/SIMD ->
//   compiler spilled (FETCH/WRITE doubled, 184us). Fix: loop order ks -> nt -> mt
//   with wf loaded JUST-IN-TIME (single use, never array-resident). Live state
//   = acc 80 + af[4] 32 + temps ~= 150 <= 168 -> (256,3) without spill.
//   3 blocks/CU (LDS 51200*3 = 153600 <= 163840).
// R5/R6: resubmits — R4/R5 benches failed on infra (container/push-path flaky;
//   R1 timing already showed 1300-2000s pushes). Kernel never executed.

#define NB 262144

typedef __attribute__((ext_vector_type(8))) short s8v;
typedef __attribute__((ext_vector_type(4))) short s4v;
typedef __attribute__((ext_vector_type(4))) float f4v;

__device__ __forceinline__ float bf2f(unsigned short s) {
  unsigned int u = ((unsigned int)s) << 16;
  return __uint_as_float(u);
}
__device__ __forceinline__ unsigned short f2bf(float f) {
  unsigned int u = __float_as_uint(f);
  u += 0x7fffu + ((u >> 16) & 1u);
  return (unsigned short)(u >> 16);
}

// ---------------- prep1: M = -0.5(Q+G^TG+eps I)+S (fp32), HtH (fp32), W zero pad ----------------
__global__ __launch_bounds__(256) void k_prep1(
    const float* __restrict__ Q, const float* __restrict__ S,
    const float* __restrict__ G, const float* __restrict__ H,
    float* __restrict__ Mf, float* __restrict__ HtH, unsigned short* __restrict__ W)
{
  const int bid = blockIdx.x, tid = threadIdx.x;
  if (bid < 64) {
    const int idx = bid * 256 + tid;
    const int j = idx >> 7, k = idx & 127;
    float g = 0.f;
    #pragma unroll 4
    for (int i = 0; i < 32; ++i)
      g += G[i * 128 + j] * G[i * 128 + k];
    Mf[idx] = -0.5f * (Q[idx] + g + ((j == k) ? 1e-4f : 0.f)) + S[idx];
  } else {
    const int e = (bid - 64) * 256 + tid;  // 0..4095
    const int a = e >> 6, b = e & 63;
    float s = 0.f;
    #pragma unroll 4
    for (int r = 0; r < 128; ++r)
      s += H[r * 64 + a] * H[r * 64 + b];
    HtH[e] = s;
    if (bid == 64) {
      for (int i = 0; i < 8; ++i) {
        int e2 = i * 256 + tid;  // 0..2047
        int n = 128 + (e2 >> 6), kk = 128 + (e2 & 63);
        W[n * 192 + kk] = 0;
      }
    }
  }
}

// ---------------- prepAC: A = M@P, C = G@P -> W (bf16) ----------------
__global__ __launch_bounds__(256) void k_prepAC(
    const float* __restrict__ Mf, const float* __restrict__ P,
    const float* __restrict__ G, unsigned short* __restrict__ W)
{
  const int bid = blockIdx.x, tid = threadIdx.x;
  if (bid < 64) {
    const int idx = bid * 256 + tid;
    const int n = idx >> 7, k = idx & 127;
    float s = 0.f;
    #pragma unroll 4
    for (int l = 0; l < 128; ++l)
      s += Mf[n * 128 + l] * P[l * 128 + k];
    W[n * 192 + k] = f2bf(s);
  } else {
    for (int i = 0; i < 4; ++i) {
      int e = (bid - 64) * 1024 + i * 256 + tid;  // 0..4095
      int j = e >> 7, k = e & 127;
      float s = 0.f;
      #pragma unroll 4
      for (int l = 0; l < 128; ++l)
        s += G[j * 128 + l] * P[l * 128 + k];
      W[(128 + j) * 192 + k] = f2bf(s);
    }
  }
}

// ---------------- prep23: fused power iteration + Chebyshev sqrtm(Q)@Htilde -> W B-part ----------------
__global__ __launch_bounds__(1024) void k_prep23(
    const float* __restrict__ Qg, const float* __restrict__ Hg,
    const float* __restrict__ HtHg, unsigned short* __restrict__ W)
{
  __shared__ char smem[65536];
  unsigned short* Xs = (unsigned short*)smem;            // [0,32768): 128x128 swizzled
  unsigned short* V0s = (unsigned short*)(smem + 32768); // 64x128 swizzled (V^T)
  unsigned short* V1s = (unsigned short*)(smem + 49152);
  float* vQ = (float*)(smem + 32768);   // overlap V region (power phase only)
  float* wQ = (float*)(smem + 33280);
  float* vH = (float*)(smem + 33792);
  float* wH = (float*)(smem + 34048);
  float* red = (float*)(smem + 34304);
  float* HtHs = (float*)(smem + 49152); // overlaps V1s (power phase only)

  const int tid = threadIdx.x;
  const int lane = tid & 63;
  const int wv = tid >> 6;

  // load Q -> Xs (swizzled: logical chunk c of row m stored at chunk c ^ (m&7))
  for (int i = 0; i < 16; ++i) {
    int e = i * 1024 + tid;
    int m = e >> 7, k = e & 127;
    Xs[m * 128 + (((k >> 3) ^ (m & 7)) << 3) + (k & 7)] = f2bf(Qg[e]);
  }
  // HtH prescaled by 1/256 so 32 unnormalized matvecs stay in fp32 range
  for (int i = 0; i < 4; ++i) HtHs[i * 1024 + tid] = HtHg[i * 1024 + tid] * 0.00390625f;
  if (tid < 128) vQ[tid] = (float)((tid * 1103515245u + 12345u) & 0xffffu) * (1.f / 65536.f) + 0.05f;
  if (tid < 64)  vH[tid] = (float)((tid * 2654435761u + 911u) & 0xffffu) * (1.f / 65536.f) + 0.05f;
  __syncthreads();

  // ---- fused unnormalized power iteration: Q on tid<512, HtH on tid>=512 ----
  // 32 steps, ONE barrier per step. Exact 2^-k rescale at step 16 (range control
  // only; lam read from ||v32||/||v31||, both post-rescale, so ratio unaffected).
  float* qin = vQ; float* qout = wQ;
  float* hin = vH; float* hout = wH;
  for (int it = 0; it < 32; ++it) {
    if (tid < 512) {
      const int row = tid >> 2, sub = tid & 3;   // 128 rows x 4 subs (32 k each)
      float p = 0.f;
      #pragma unroll
      for (int c = 0; c < 4; ++c) {
        const int ch = sub * 4 + c;
        const s8v q = *(const s8v*)&Xs[row * 128 + ((ch ^ (row & 7)) << 3)];
        const f4v a = *(const f4v*)&qin[ch * 8];
        const f4v b = *(const f4v*)&qin[ch * 8 + 4];
        p += bf2f((unsigned short)q[0]) * a[0];
        p += bf2f((unsigned short)q[1]) * a[1];
        p += bf2f((unsigned short)q[2]) * a[2];
        p += bf2f((unsigned short)q[3]) * a[3];
        p += bf2f((unsigned short)q[4]) * b[0];
        p += bf2f((unsigned short)q[5]) * b[1];
        p += bf2f((unsigned short)q[6]) * b[2];
        p += bf2f((unsigned short)q[7]) * b[3];
      }
      p += __shfl_xor(p, 1); p += __shfl_xor(p, 2);
      if (it == 16) p *= 0x1p-32f;
      if (sub == 0) qout[row] = p;
    } else {
      const int idx = tid - 512;
      const int row = idx >> 3, sub = idx & 7;   // 64 rows x 8 subs (8 k each)
      const f4v a  = *(const f4v*)&HtHs[row * 64 + sub * 8];
      const f4v b  = *(const f4v*)&HtHs[row * 64 + sub * 8 + 4];
      const f4v va = *(const f4v*)&hin[sub * 8];
      const f4v vb = *(const f4v*)&hin[sub * 8 + 4];
      float p = a[0] * va[0] + a[1] * va[1] + a[2] * va[2] + a[3] * va[3]
              + b[0] * vb[0] + b[1] * vb[1] + b[2] * vb[2] + b[3] * vb[3];
      p += __shfl_xor(p, 1); p += __shfl_xor(p, 2); p += __shfl_xor(p, 4);
      if (it == 16) p *= 0x1p-8f;
      if (sub == 0) hout[row] = p;
    }
    __syncthreads();
    float* t;
    t = qin; qin = qout; qout = t;
    t = hin; hin = hout; hout = t;
  }
  // after loop: qin = v32, qout = v31 (same for hin/hout)

  // ---- norms of last two iterates -> lamQ, lamH ----
  {
    float s = 0.f;
    if (wv == 0)      { float a = qin[lane],  b = qin[lane + 64];  s = a * a + b * b; }
    else if (wv == 1) { float a = qout[lane], b = qout[lane + 64]; s = a * a + b * b; }
    else if (wv == 2) { float a = hin[lane];  s = a * a; }
    else if (wv == 3) { float a = hout[lane]; s = a * a; }
    if (wv < 4) {
      s += __shfl_xor(s, 1); s += __shfl_xor(s, 2); s += __shfl_xor(s, 4);
      s += __shfl_xor(s, 8); s += __shfl_xor(s, 16); s += __shfl_xor(s, 32);
      if (lane == 0) red[wv] = s;
    }
  }
  __syncthreads();
  if (tid == 0) {
    red[4] = sqrtf(red[0] / red[1]);           // lamQ
    red[5] = 256.f * sqrtf(red[2] / red[3]);   // lamH (undo 1/256 prescale)
  }
  __syncthreads();
  const float bb = 1.10f * red[4];   // Chebyshev interval [0, bb]
  const float sqrtb = sqrtf(bb);
  const float invden = 1.f / (1.01f * sqrtf(red[5]));
  __syncthreads();  // all threads hold bb/invden in regs before V0s clobbers red

  // ---- phase C: X = (2/b)Q - I in place; V0 = Htilde^T; Chebyshev recurrence ----
  for (int i = 0; i < 16; ++i) {
    int e = i * 1024 + tid;
    int m = e >> 7, k = e & 127;
    int a = m * 128 + (((k >> 3) ^ (m & 7)) << 3) + (k & 7);
    float q = bf2f(Xs[a]);
    Xs[a] = f2bf(q * (2.f / bb) - ((m == k) ? 1.f : 0.f));
  }
  for (int i = 0; i < 8; ++i) {
    int e = i * 1024 + tid;
    int j = e & 63, m = e >> 6;
    V0s[j * 128 + (((m >> 3) ^ (j & 7)) << 3) + (m & 7)] = f2bf(Hg[m * 64 + j] * invden);
  }
  const int t0 = wv * 2;   // 2 of 32 16x16 tiles per wave (8 m-tiles x 4 n-tiles)
  float baccR[2][4];
  #pragma unroll
  for (int tt = 0; tt < 2; ++tt) {
    int mt = (t0 + tt) >> 2, nt = (t0 + tt) & 3;
    int n = nt * 16 + (lane & 15);
    int mb = mt * 16 + ((lane >> 4) << 2);
    #pragma unroll
    for (int i = 0; i < 4; ++i)
      baccR[tt][i] = 0.63661977f * Hg[(mb + i) * 64 + n] * invden;  // a0 * T0 term
  }
  __syncthreads();

  unsigned short* Vc = V0s;
  unsigned short* Vp = V1s;
  for (int k = 1; k <= 32; ++k) {
    const float ck = ((k & 1) ? 1.0f : -1.0f) / (3.14159265f * ((float)(k * k) - 0.25f));
    #pragma unroll
    for (int tt = 0; tt < 2; ++tt) {
      const int mt = (t0 + tt) >> 2, nt = (t0 + tt) & 3;
      f4v acc = {0.f, 0.f, 0.f, 0.f};
      const int arow = mt * 16 + (lane & 15);
      const int brow = nt * 16 + (lane & 15);
      #pragma unroll
      for (int ks = 0; ks < 4; ++ks) {
        int kc = ks * 4 + (lane >> 4);
        s8v af = *(const s8v*)&Xs[arow * 128 + ((kc ^ (arow & 7)) << 3)];
        s8v bf = *(const s8v*)&Vc[brow * 128 + ((kc ^ (brow & 7)) << 3)];
        acc = __builtin_amdgcn_mfma_f32_16x16x32_bf16(af, bf, acc, 0, 0, 0);
      }
      const int n = brow;
      const int mb = mt * 16 + ((lane >> 4) << 2);
      const int vaddr = n * 128 + (((mb >> 3) ^ (n & 7)) << 3) + (mb & 7);
      float nv[4];
      if (k == 1) {
        #pragma unroll
        for (int i = 0; i < 4; ++i) nv[i] = acc[i];
      } else {
        s4v ov = *(const s4v*)&Vp[vaddr];
        #pragma unroll
        for (int i = 0; i < 4; ++i) nv[i] = 2.f * acc[i] - bf2f((unsigned short)ov[i]);
      }
      s4v st;
      #pragma unroll
      for (int i = 0; i < 4; ++i) { st[i] = (short)f2bf(nv[i]); baccR[tt][i] += ck * nv[i]; }
      *(s4v*)&Vp[vaddr] = st;
    }
    __syncthreads();
    unsigned short* t = Vc; Vc = Vp; Vp = t;
  }

  // ---- phase D: B = sqrt(b) * sum -> W[m][128+j] ----
  #pragma unroll
  for (int tt = 0; tt < 2; ++tt) {
    const int mt = (t0 + tt) >> 2, nt = (t0 + tt) & 3;
    const int n = nt * 16 + (lane & 15);
    const int mb = mt * 16 + ((lane >> 4) << 2);
    #pragma unroll
    for (int i = 0; i < 4; ++i)
      W[(mb + i) * 192 + 128 + n] = f2bf(sqrtb * baccR[tt][i]);
  }
}

// ---------------- main: Out[N][160] = [x|u] @ W^T ; fp32 in, fp32 out ----------------
// 3 blocks/CU: LDS 51200*3 <= 163840; regs: acc 80 (AGPR) + af[4] 32 + jit wf +
// temps ~= 150 <= 168 (512/3). wf is single-use (loaded inside nt loop) so the
// allocator can delay loads instead of spilling (R1 lesson).
__global__ __launch_bounds__(256, 3) void k_main(
    const float* __restrict__ x, const float* __restrict__ u,
    const unsigned short* __restrict__ W, float* __restrict__ out)
{
  __shared__ char smraw[128 * 200 * 2];          // 51200 B
  unsigned short* sm = (unsigned short*)smraw;    // staging: [128 rows][200], cols 0..127 x, 128..191 u
  float* fb = (float*)smraw;                      // epilogue reuse: [64 rows][164] fp32 = 41984 B

  const int tid = threadIdx.x, lane = tid & 63, w = tid >> 6;
  const int mw = w & 1, nw = w >> 1;
  const int base = blockIdx.x * 128;

  // stage x,u tiles: fp32 16B loads, convert to bf16
  #pragma unroll
  for (int p = 0; p < 16; ++p) {
    int g = p * 256 + tid; int r = g >> 5, c = g & 31;
    f4v v = *(const f4v*)&x[(size_t)(base + r) * 128 + c * 4];
    s4v b;
    #pragma unroll
    for (int i = 0; i < 4; ++i) b[i] = (short)f2bf(v[i]);
    *(s4v*)&sm[r * 200 + c * 4] = b;
  }
  #pragma unroll
  for (int p = 0; p < 8; ++p) {
    int g = p * 256 + tid; int r = g >> 4, c = g & 15;
    f4v v = *(const f4v*)&u[(size_t)(base + r) * 64 + c * 4];
    s4v b;
    #pragma unroll
    for (int i = 0; i < 4; ++i) b[i] = (short)f2bf(v[i]);
    *(s4v*)&sm[r * 200 + 128 + c * 4] = b;
  }
  __syncthreads();

  f4v acc[4][5];
  #pragma unroll
  for (int mt = 0; mt < 4; ++mt)
    #pragma unroll
    for (int nt = 0; nt < 5; ++nt)
      acc[mt][nt] = (f4v){0.f, 0.f, 0.f, 0.f};

  const int n0 = nw * 80 + (lane & 15);
  const int kof = (lane >> 4) * 8;
  const int row0 = mw * 64 + (lane & 15);
  #pragma unroll
  for (int ks = 0; ks < 6; ++ks) {
    // 4 A-fragments for this k-step (live: 32 VGPRs)
    s8v af0 = *(const s8v*)&sm[(row0     ) * 200 + ks * 32 + kof];
    s8v af1 = *(const s8v*)&sm[(row0 + 16) * 200 + ks * 32 + kof];
    s8v af2 = *(const s8v*)&sm[(row0 + 32) * 200 + ks * 32 + kof];
    s8v af3 = *(const s8v*)&sm[(row0 + 48) * 200 + ks * 32 + kof];
    #pragma unroll
    for (int nt = 0; nt < 5; ++nt) {
      // weight fragment: single use, loaded just-in-time from L1/L2-hot W
      s8v wfv = *(const s8v*)&W[(n0 + nt * 16) * 192 + ks * 32 + kof];
      acc[0][nt] = __builtin_amdgcn_mfma_f32_16x16x32_bf16(af0, wfv, acc[0][nt], 0, 0, 0);
      acc[1][nt] = __builtin_amdgcn_mfma_f32_16x16x32_bf16(af1, wfv, acc[1][nt], 0, 0, 0);
      acc[2][nt] = __builtin_amdgcn_mfma_f32_16x16x32_bf16(af2, wfv, acc[2][nt], 0, 0, 0);
      acc[3][nt] = __builtin_amdgcn_mfma_f32_16x16x32_bf16(af3, wfv, acc[3][nt], 0, 0, 0);
    }
  }

  // epilogue: two passes of 64 rows through fp32 LDS, then coalesced float4 stores
  float* const yout = out + (size_t)NB * 128;
  #pragma unroll
  for (int pass = 0; pass < 2; ++pass) {
    __syncthreads();
    if (mw == pass) {
      #pragma unroll
      for (int mt = 0; mt < 4; ++mt)
        #pragma unroll
        for (int nt = 0; nt < 5; ++nt) {
          const int rr = mt * 16 + ((lane >> 4) << 2);        // row within this 64-row pass
          const int cc = nw * 80 + nt * 16 + (lane & 15);
          #pragma unroll
          for (int i = 0; i < 4; ++i)
            fb[(rr + i) * 164 + cc] = acc[mt][nt][i];
        }
    }
    __syncthreads();
    const int rb = base + pass * 64;
    #pragma unroll
    for (int p = 0; p < 8; ++p) {   // dx: 64 rows x 128 cols fp32
      int g = p * 256 + tid; int r = g >> 5, c = g & 31;
      *(f4v*)&out[(size_t)(rb + r) * 128 + c * 4] = *(const f4v*)&fb[r * 164 + c * 4];
    }
    #pragma unroll
    for (int p = 0; p < 2; ++p) {   // y: 64 rows x 32 cols fp32
      int g = p * 256 + tid; int r = g >> 3, c = g & 7;
      *(f4v*)&yout[(size_t)(rb + r) * 32 + c * 4] = *(const f4v*)&fb[r * 164 + 128 + c * 4];
    }
  }
}

extern "C" void kernel_launch(void* const* d_in, const int* in_sizes, int n_in,
                              void* d_out, int out_size, void* d_ws, size_t ws_size,
                              hipStream_t stream) {
  // identify unambiguous inputs by element count (insurance against ordering surprises);
  // the three 128x128 matrices keep dict order Q,P,S per harness contract.
  const float *u = nullptr, *x = nullptr, *G = nullptr, *H = nullptr;
  const float* sq[3] = {nullptr, nullptr, nullptr};
  int nsq = 0;
  for (int i = 0; i < n_in; ++i) {
    const float* p = (const float*)d_in[i];
    switch (in_sizes[i]) {
      case NB * 64:  u = p; break;
      case NB * 128: x = p; break;
      case 32 * 128: G = p; break;
      case 128 * 64: H = p; break;
      case 128 * 128: if (nsq < 3) sq[nsq++] = p; break;
      default: break;
    }
  }
  const float* Q = sq[0];
  const float* P = sq[1];
  const float* S = sq[2];

  char* ws = (char*)d_ws;
  unsigned short* W = (unsigned short*)ws;        // 160*192 bf16 = 61440 B
  float* HtH = (float*)(ws + 61440);              // 64*64 fp32  = 16384 B
  float* Mf  = (float*)(ws + 77824);              // 128*128 fp32 = 65536 B
  float* out = (float*)d_out;

  k_prep1 <<<80,   256,  0, stream>>>(Q, S, G, H, Mf, HtH, W);
  k_prepAC<<<68,   256,  0, stream>>>(Mf, P, G, W);
  k_prep23<<<1,    1024, 0, stream>>>(Q, H, HtH, W);
  k_main  <<<2048, 256,  0, stream>>>(x, u, W, out);
}